// Round 12
// baseline (667.333 us; speedup 1.0000x reference)
//
#include <hip/hip_runtime.h>
#include <hip/hip_bf16.h>

#define NB 4
#define NRQ 32768      // per-batch q-side rows  (n*4)
#define NKF 131072     // per-batch feats rows   (n*16)

using u16 = unsigned short;
typedef short bf16x8 __attribute__((ext_vector_type(8)));
typedef float f32x4  __attribute__((ext_vector_type(4)));
typedef u16   u16x8  __attribute__((ext_vector_type(8)));
typedef u16   u16x4  __attribute__((ext_vector_type(4)));
typedef u16   u16x2  __attribute__((ext_vector_type(2)));

#if defined(__has_builtin)
#  if __has_builtin(__builtin_amdgcn_fdot2_f32_bf16)
#    define HAVE_DOT2 1
#  endif
#endif
#ifndef HAVE_DOT2
#  define HAVE_DOT2 0
#endif

#if HAVE_DOT2
typedef __bf16 bfv2 __attribute__((ext_vector_type(2)));
union bpack { bf16x8 v; bfv2 p[4]; };
__device__ __forceinline__ float dot2(bfv2 a, bfv2 b, float c){
  return __builtin_amdgcn_fdot2_f32_bf16(a, b, c, false);
}
#endif
union vpack { bf16x8 v; u16 e[8]; };

__device__ __forceinline__ u16 f2b(float f){
  __hip_bfloat16 h = __float2bfloat16(f);   // native cvt, RNE
  return *reinterpret_cast<u16*>(&h);
}
__device__ __forceinline__ float b2f(u16 v){
  return __uint_as_float(((unsigned)v) << 16);
}

#define GLOAD16(g, l) __builtin_amdgcn_global_load_lds( \
    (const __attribute__((address_space(1))) unsigned int*)(g), \
    (__attribute__((address_space(3))) unsigned int*)(l), 16, 0, 0)

// ---------------------------------------------------------------------------
// Weight preconvert fp32 -> bf16 (stacked) + bias stack + stat zero (merged)
// ---------------------------------------------------------------------------
__global__ __launch_bounds__(256) void cvtW_k(
    const float* __restrict__ Wk, const float* __restrict__ Wv,
    const float* __restrict__ Wq, const float* __restrict__ W1,
    const float* __restrict__ W2, u16* __restrict__ wT,
    const float* __restrict__ bk, const float* __restrict__ bv,
    float* __restrict__ bKV, float* __restrict__ stats)
{
  if (blockIdx.x >= 224){
    int i = (blockIdx.x - 224) * 256 + threadIdx.x;
    if (i < 512)       bKV[i] = (i < 256) ? bk[i] : bv[i - 256];
    else if (i < 1536) stats[i - 512] = 0.f;
    return;
  }
  long e = ((long)blockIdx.x * 256 + threadIdx.x) * 8;
  const float* src; long off;
  if      (e < 65536)  { src = Wk; off = e; }
  else if (e < 131072) { src = Wv; off = e - 65536; }
  else if (e < 196608) { src = Wq; off = e - 131072; }
  else if (e < 327680) { src = W1; off = e - 196608; }
  else                 { src = W2; off = e - 327680; }
  float4 f0 = *reinterpret_cast<const float4*>(src + off);
  float4 f1 = *reinterpret_cast<const float4*>(src + off + 4);
  u16x8 p;
  p[0]=f2b(f0.x); p[1]=f2b(f0.y); p[2]=f2b(f0.z); p[3]=f2b(f0.w);
  p[4]=f2b(f1.x); p[5]=f2b(f1.y); p[6]=f2b(f1.z); p[7]=f2b(f1.w);
  *reinterpret_cast<u16x8*>(wT + e) = p;
}

// ---------------------------------------------------------------------------
// Transpose+convert: in fp32 [B][256][NCtot] -> out bf16 [B][NCtot][256].
// ---------------------------------------------------------------------------
__global__ __launch_bounds__(256) void transpose_k(
    const float* __restrict__ in, u16* __restrict__ out,
    int NCtot, long outBatch)
{
  __shared__ u16 sT[64][264];
  const int t = threadIdx.x, b = blockIdx.y;
  const int nr0 = blockIdx.x * 64;
  const int cb = t >> 2, nrq = t & 3;
  const long ib = (long)b * 256 * NCtot + nr0;

  #pragma unroll
  for (int ci = 0; ci < 4; ++ci){
    const int c = cb + ci * 64;
    const float* src = in + ib + (long)c * NCtot + nrq * 16;
    #pragma unroll
    for (int j = 0; j < 4; ++j){
      float4 f = *reinterpret_cast<const float4*>(src + j * 4);
      int nr = nrq * 16 + j * 4;
      sT[nr+0][c] = f2b(f.x); sT[nr+1][c] = f2b(f.y);
      sT[nr+2][c] = f2b(f.z); sT[nr+3][c] = f2b(f.w);
    }
  }
  __syncthreads();
  const int row = t >> 2, qtr = t & 3;
  u16* orow = out + (long)b * outBatch + (long)(nr0 + row) * 256 + qtr * 64;
  #pragma unroll
  for (int i = 0; i < 8; ++i)
    *reinterpret_cast<u16x8*>(orow + i * 8) =
        *reinterpret_cast<const u16x8*>(&sT[row][qtr * 64 + i * 8]);
}

// ---------------------------------------------------------------------------
// GEMM: C[rows x NCH] = A[rows x KD] (bf16 k-contig) * Wb[NCH x KD]^T + bias.
// MODE 0: bf16 C. MODE 1: + per-ch sum/sumsq atomics.
// MODE 3: A reg-staged with per-k BN scale/shift+relu; epilogue
//         out = relu(acc+bias+residT) -> fp32 outF [ch][row].
// ---------------------------------------------------------------------------
template<int MODE, int KD>
__global__ __launch_bounds__(256) void gemm_k(
    const u16* __restrict__ A, long aBatch, int chTiles,
    const u16* __restrict__ Wb, const float* __restrict__ bias,
    u16* __restrict__ outH, long oBatch, int NCH,
    float* __restrict__ statSum, float* __restrict__ statSq,
    const float* __restrict__ xsc, const float* __restrict__ xsh,
    const u16* __restrict__ residT,
    float* __restrict__ outF, long fBatch)
{
  __shared__ __align__(16) char sA[2][16384];
  __shared__ __align__(16) char sB[2][16384];

  const int t = threadIdx.x, lane = t & 63, wid = t >> 6;
  const int wm = wid >> 1, wn = wid & 1;
  const int b = blockIdx.z;

  const int nwg = gridDim.x, orig = blockIdx.x;
  const int qq = nwg >> 3, rr = nwg & 7, xcd = orig & 7, pos = orig >> 3;
  const int wg = (xcd < rr ? xcd * (qq + 1) : rr * (qq + 1) + (xcd - rr) * qq) + pos;
  const int rowT = wg / chTiles, chT = wg % chTiles;

  const u16* Ab = A + (long)b * aBatch + (long)rowT * 128 * KD;
  const u16* Wt = Wb + (long)chT * 128 * KD;
  const int sub = lane >> 3, kc8 = ((lane & 7) ^ sub) * 8;

  f32x4 acc[4][4];
  #pragma unroll
  for (int i = 0; i < 4; ++i)
    #pragma unroll
    for (int j = 0; j < 4; ++j) acc[i][j] = (f32x4){0.f,0.f,0.f,0.f};

  auto STAGE = [&](int buf, int ks){
    const int k0 = ks * 64;
    if constexpr (MODE == 3){
      const int wrow = t >> 1, whalf = t & 1;
      const u16* arow = Ab + (long)wrow * KD + k0 + whalf * 32;
      #pragma unroll
      for (int i = 0; i < 4; ++i){
        u16x8 v = *reinterpret_cast<const u16x8*>(arow + i * 8);
        const int kb = k0 + whalf*32 + i*8;
        float4 s0 = *reinterpret_cast<const float4*>(xsc + kb);
        float4 s1 = *reinterpret_cast<const float4*>(xsc + kb + 4);
        float4 h0 = *reinterpret_cast<const float4*>(xsh + kb);
        float4 h1 = *reinterpret_cast<const float4*>(xsh + kb + 4);
        u16x8 o;
        o[0]=f2b(fmaxf(b2f(v[0])*s0.x+h0.x,0.f));
        o[1]=f2b(fmaxf(b2f(v[1])*s0.y+h0.y,0.f));
        o[2]=f2b(fmaxf(b2f(v[2])*s0.z+h0.z,0.f));
        o[3]=f2b(fmaxf(b2f(v[3])*s0.w+h0.w,0.f));
        o[4]=f2b(fmaxf(b2f(v[4])*s1.x+h1.x,0.f));
        o[5]=f2b(fmaxf(b2f(v[5])*s1.y+h1.y,0.f));
        o[6]=f2b(fmaxf(b2f(v[6])*s1.z+h1.z,0.f));
        o[7]=f2b(fmaxf(b2f(v[7])*s1.w+h1.w,0.f));
        *reinterpret_cast<u16x8*>(
            sA[buf] + ((wrow*128 + whalf*64 + i*16) ^ ((wrow & 7) << 4))) = o;
      }
      #pragma unroll
      for (int i = 0; i < 4; ++i){
        const int chunk = wid * 4 + i;
        GLOAD16(Wt + (long)(chunk*8 + sub)*KD + k0 + kc8, sB[buf] + chunk*1024);
      }
    } else {
      #pragma unroll
      for (int i = 0; i < 4; ++i){
        const int chunk = wid * 4 + i;
        GLOAD16(Ab + (long)(chunk*8 + sub)*KD + k0 + kc8, sA[buf] + chunk*1024);
        GLOAD16(Wt + (long)(chunk*8 + sub)*KD + k0 + kc8, sB[buf] + chunk*1024);
      }
    }
  };

  constexpr int NT = KD / 64;
  STAGE(0, 0);
  __syncthreads();
  int cur = 0;
  for (int ks = 0; ks < NT; ++ks){
    if (ks + 1 < NT) STAGE(cur ^ 1, ks + 1);
    const char* pA = sA[cur]; const char* pB = sB[cur];
    #pragma unroll
    for (int kk = 0; kk < 2; ++kk){
      bf16x8 af[4], bf[4];
      #pragma unroll
      for (int mi = 0; mi < 4; ++mi){
        int m = wm*64 + mi*16 + (lane & 15);
        af[mi] = *reinterpret_cast<const bf16x8*>(
            pA + ((m*128 + kk*64 + (lane>>4)*16) ^ ((m & 7) << 4)));
      }
      #pragma unroll
      for (int ni = 0; ni < 4; ++ni){
        int c = wn*64 + ni*16 + (lane & 15);
        bf[ni] = *reinterpret_cast<const bf16x8*>(
            pB + ((c*128 + kk*64 + (lane>>4)*16) ^ ((c & 7) << 4)));
      }
      #pragma unroll
      for (int mi = 0; mi < 4; ++mi)
        #pragma unroll
        for (int ni = 0; ni < 4; ++ni)
          acc[mi][ni] = __builtin_amdgcn_mfma_f32_16x16x32_bf16(
              af[mi], bf[ni], acc[mi][ni], 0, 0, 0);
    }
    __syncthreads();
    cur ^= 1;
  }

  int chI[4]; float bv[4];
  #pragma unroll
  for (int ni = 0; ni < 4; ++ni){
    int ch = chT*128 + wn*64 + ni*16 + (lane & 15);
    chI[ni] = ch;
    bv[ni] = bias[ch];
  }
  if (MODE != 3){
    float s[4] = {0,0,0,0}, sq[4] = {0,0,0,0};
    u16* outb = outH + (long)b * oBatch;
    #pragma unroll
    for (int mi = 0; mi < 4; ++mi){
      #pragma unroll
      for (int j = 0; j < 4; ++j){
        const long row = rowT*128 + wm*64 + mi*16 + (lane>>4)*4 + j;
        #pragma unroll
        for (int ni = 0; ni < 4; ++ni){
          float v = acc[mi][ni][j] + bv[ni];
          outb[row * NCH + chI[ni]] = f2b(v);
          if (MODE == 1){ s[ni] += v; sq[ni] += v * v; }
        }
      }
    }
    if (MODE == 1){
      #pragma unroll
      for (int ni = 0; ni < 4; ++ni){
        s[ni]  += __shfl_xor(s[ni], 16);  s[ni]  += __shfl_xor(s[ni], 32);
        sq[ni] += __shfl_xor(sq[ni], 16); sq[ni] += __shfl_xor(sq[ni], 32);
      }
      if (lane < 16){
        #pragma unroll
        for (int ni = 0; ni < 4; ++ni){
          atomicAdd(&statSum[chI[ni]], s[ni]);
          atomicAdd(&statSq[chI[ni]],  sq[ni]);
        }
      }
    }
  } else {
    const u16* rb = residT + (long)b * ((long)NRQ * 256);
    #pragma unroll
    for (int mi = 0; mi < 4; ++mi){
      const int nr0 = rowT*128 + wm*64 + mi*16 + (lane>>4)*4;
      #pragma unroll
      for (int ni = 0; ni < 4; ++ni){
        float4 o;
        o.x = fmaxf(acc[mi][ni][0] + bv[ni] + b2f(rb[(long)(nr0+0)*256 + chI[ni]]), 0.f);
        o.y = fmaxf(acc[mi][ni][1] + bv[ni] + b2f(rb[(long)(nr0+1)*256 + chI[ni]]), 0.f);
        o.z = fmaxf(acc[mi][ni][2] + bv[ni] + b2f(rb[(long)(nr0+2)*256 + chI[ni]]), 0.f);
        o.w = fmaxf(acc[mi][ni][3] + bv[ni] + b2f(rb[(long)(nr0+3)*256 + chI[ni]]), 0.f);
        *reinterpret_cast<float4*>(outF + (long)b*fBatch + (long)chI[ni]*NRQ + nr0) = o;
      }
    }
  }
}

// ---------------------------------------------------------------------------
// Fused kv-projection + attention, v7: 1024-thread block, 128 rows (8 pts)
// x 512 ch. Halves LDS W-read instructions per FLOP vs 64-row version
// (LDS-issue-bound per R11 arithmetic). BK=32, 8 K-steps, A pitch-72 dbuf,
// W dbuf via global_load_lds. sK pitch 528 NO XOR (2-way free); sV 520.
// Counted-vmcnt barriers + depth-2 feats prefetch + setprio (from v6).
// LDS 139.5KB -> 1 block/CU = 16 waves (same occupancy as v6's 2x8).
// ---------------------------------------------------------------------------
__global__ __launch_bounds__(1024, 1) void kvattn_k(
    const float* __restrict__ feats, const u16* __restrict__ wKV,
    const float* __restrict__ bKV, const u16* __restrict__ qT,
    const u16* __restrict__ qrT, u16* __restrict__ aggT)
{
  __shared__ __align__(16) char LDS[142848];
  char*  sAg = LDS;                     // 2 x 128 x 72 = 18432
  char*  sW  = LDS + 18432;             // 2 x 32768 = 65536 (ends 83968)
  char*  sK  = LDS;                     // attn: [128 r][528B] plain
  char*  sV  = LDS + 67584;             // attn: [128 r][520B] plain (ends 134144)
  float* sSf = (float*)(LDS + 134144);  // P fp32: [32 ph][68 dw] (8704B)

  const int t = threadIdx.x, lane = t & 63, wid = t >> 6;   // wid 0..15
  const int wr = wid >> 2, wc = wid & 3;       // 4 x 4 waves for GEMM
  const int b = blockIdx.y;
  const long row0 = (long)blockIdx.x * 128;

  const int chL = t >> 5, nq = t & 31;         // k-elem, row-quad
  const float* fbase = feats + (long)b * 256 * NKF + row0 + nq * 4;

  auto STAGEW = [&](int buf, int ks){
    const int k0 = ks * 32;
    #pragma unroll
    for (int i = 0; i < 2; ++i){
      const int cw = wid * 2 + i;                   // 32 chunks x 1KB
      const int ch = cw * 16 + (lane >> 2), jd = lane & 3;
      GLOAD16(wKV + (long)ch * 256 + k0 + ((jd ^ ((ch >> 1) & 3)) * 8),
              sW + buf * 32768 + cw * 1024);
    }
  };
  auto WRITEA = [&](int buf, float4 f){
    #pragma unroll
    for (int i = 0; i < 4; ++i){
      const int r = nq * 4 + i;
      float e = (i == 0) ? f.x : (i == 1) ? f.y : (i == 2) ? f.z : f.w;
      *reinterpret_cast<u16*>(sAg + buf*9216 + r*72 + chL*2) = f2b(e);
    }
  };

  f32x4 acc[2][8];
  #pragma unroll
  for (int i = 0; i < 2; ++i)
    #pragma unroll
    for (int j = 0; j < 8; ++j) acc[i][j] = (f32x4){0.f,0.f,0.f,0.f};

  float4 aReg0, aReg1;
  {
    aReg0 = *reinterpret_cast<const float4*>(fbase + (long)chL * NKF);
    aReg1 = *reinterpret_cast<const float4*>(fbase + (long)(32 + chL) * NKF);
    STAGEW(0, 0);
    WRITEA(0, aReg0);
  }
  __syncthreads();

  int cur = 0;
  const int jq = lane >> 4;
  #pragma unroll
  for (int ks = 0; ks < 8; ++ks){
    if (ks < 7) STAGEW(cur ^ 1, ks + 1);
    __builtin_amdgcn_sched_barrier(0);
    if (ks < 6){
      float4 f = *reinterpret_cast<const float4*>(
          fbase + (long)((ks + 2) * 32 + chL) * NKF);
      if ((ks & 1) == 0) aReg0 = f; else aReg1 = f;
    }
    const char* pA = sAg + cur * 9216;
    const char* pW = sW  + cur * 32768;
    bf16x8 af[2];
    #pragma unroll
    for (int mi = 0; mi < 2; ++mi){
      const int m = wr*32 + mi*16 + (lane & 15);
      af[mi] = *reinterpret_cast<const bf16x8*>(pA + m*72 + jq*16);
    }
    __builtin_amdgcn_s_setprio(1);
    #pragma unroll
    for (int ni = 0; ni < 8; ++ni){
      const int ch = wc*128 + ni*16 + (lane & 15);
      bf16x8 bf = *reinterpret_cast<const bf16x8*>(
          pW + ch*64 + (((jq ^ ((ch>>1)&3)) * 16)));
      acc[0][ni] = __builtin_amdgcn_mfma_f32_16x16x32_bf16(af[0], bf, acc[0][ni], 0,0,0);
      acc[1][ni] = __builtin_amdgcn_mfma_f32_16x16x32_bf16(af[1], bf, acc[1][ni], 0,0,0);
    }
    __builtin_amdgcn_s_setprio(0);
    if (ks < 7) WRITEA(cur ^ 1, ((ks + 1) & 1) == 0 ? aReg0 : aReg1);
    if (ks < 6){
      asm volatile("s_waitcnt vmcnt(1) lgkmcnt(0)" ::: "memory");
    } else {
      asm volatile("s_waitcnt vmcnt(0) lgkmcnt(0)" ::: "memory");
    }
    __builtin_amdgcn_s_barrier();
    cur ^= 1;
  }

  // ---- C (+bias) -> sK (ch 0-255) / sV (ch 256-511), plain pitches
  {
    float bv[8];
    #pragma unroll
    for (int ni = 0; ni < 8; ++ni) bv[ni] = bKV[wc*128 + ni*16 + (lane & 15)];
    if (wc < 2){
      #pragma unroll
      for (int mi = 0; mi < 2; ++mi){
        #pragma unroll
        for (int ni = 0; ni < 8; ++ni){
          const int ch = wc*128 + ni*16 + (lane & 15);
          #pragma unroll
          for (int j = 0; j < 4; ++j){
            const int r = wr*32 + mi*16 + (lane>>4)*4 + j;
            *reinterpret_cast<u16*>(sK + r*528 + ch*2) =
                f2b(acc[mi][ni][j] + bv[ni]);
          }
        }
      }
    } else {
      #pragma unroll
      for (int mi = 0; mi < 2; ++mi){
        #pragma unroll
        for (int ni = 0; ni < 8; ++ni){
          const int cv = (wc-2)*128 + ni*16 + (lane & 15);
          #pragma unroll
          for (int j = 0; j < 4; ++j){
            const int r = wr*32 + mi*16 + (lane>>4)*4 + j;
            *reinterpret_cast<u16*>(sV + r*520 + cv*2) =
                f2b(acc[mi][ni][j] + bv[ni]);
          }
        }
      }
    }
  }

  // residual prefetch (consumed in phase B; latency hidden under phase A)
  const int p = wid >> 1, rh = wid & 1;        // 8 points x 2 waves
  const int nqg = blockIdx.x * 8 + p;
  const int c0 = rh*128 + lane*2;
  u16x2 rq[4];
  {
    const u16* rqp = qrT + ((long)b*NRQ + (long)nqg*4)*256 + c0;
    #pragma unroll
    for (int r = 0; r < 4; ++r)
      rq[r] = *reinterpret_cast<const u16x2*>(rqp + r*256);
  }
  __syncthreads();

  // ---- phase A: logits + softmax; lane = (h, kk)
  {
    const int h = lane >> 4, kk = lane & 15;
    const u16* qb = qT + ((long)b*NRQ + (long)nqg*4 + rh*2)*256 + h*64;
    const char* kr = sK + (p*16 + kk)*528 + h*128;
    float l0 = 0.f, l1 = 0.f;
#if HAVE_DOT2
    #pragma unroll
    for (int d8 = 0; d8 < 8; ++d8){
      bpack K8, Q0, Q1;
      K8.v = *reinterpret_cast<const bf16x8*>(kr + d8*16);
      Q0.v = *reinterpret_cast<const bf16x8*>(qb + d8*8);
      Q1.v = *reinterpret_cast<const bf16x8*>(qb + 256 + d8*8);
      #pragma unroll
      for (int pi = 0; pi < 4; ++pi){
        l0 = dot2(K8.p[pi], Q0.p[pi], l0);
        l1 = dot2(K8.p[pi], Q1.p[pi], l1);
      }
    }
#else
    #pragma unroll
    for (int d8 = 0; d8 < 8; ++d8){
      vpack K8, Q0, Q1;
      K8.v = *reinterpret_cast<const bf16x8*>(kr + d8*16);
      Q0.v = *reinterpret_cast<const bf16x8*>(qb + d8*8);
      Q1.v = *reinterpret_cast<const bf16x8*>(qb + 256 + d8*8);
      #pragma unroll
      for (int e = 0; e < 8; ++e){
        float kf = b2f(K8.e[e]);
        l0 = fmaf(kf, b2f(Q0.e[e]), l0);
        l1 = fmaf(kf, b2f(Q1.e[e]), l1);
      }
    }
#endif
    float pr[2]; float lv[2] = {l0, l1};
    #pragma unroll
    for (int r = 0; r < 2; ++r){
      float x = lv[r] * 0.125f;
      float m = x;
      #pragma unroll
      for (int off = 1; off < 16; off <<= 1) m = fmaxf(m, __shfl_xor(m, off));
      float e = __expf(x - m);
      float ssum = e;
      #pragma unroll
      for (int off = 1; off < 16; off <<= 1) ssum += __shfl_xor(ssum, off);
      pr[r] = e / ssum;
    }
    *reinterpret_cast<float2*>(sSf + (p*4 + h)*68 + kk*4 + rh*2) =
        make_float2(pr[0], pr[1]);
  }
  __syncthreads();

  // ---- phase B: agg = v @ soft^T + qrT residual. lane -> 2 channels
  {
    const int h = c0 >> 6;
    const char* vrow = sV + (p*16)*520;
    const float* ss = sSf + (p*4 + h)*68;
    float a[4][2] = {};
    #pragma unroll
    for (int kk = 0; kk < 16; ++kk){
      u16x2 vv = *reinterpret_cast<const u16x2*>(vrow + kk*520 + c0*2);
      float4 sv = *reinterpret_cast<const float4*>(ss + kk*4);
      float v0 = b2f(vv[0]), v1 = b2f(vv[1]);
      a[0][0] += sv.x*v0; a[0][1] += sv.x*v1;
      a[1][0] += sv.y*v0; a[1][1] += sv.y*v1;
      a[2][0] += sv.z*v0; a[2][1] += sv.z*v1;
      a[3][0] += sv.w*v0; a[3][1] += sv.w*v1;
    }
    u16* ob = aggT + ((long)b*NRQ + (long)nqg*4)*256 + c0;
    #pragma unroll
    for (int r = 0; r < 4; ++r){
      u16x2 pk;
      pk[0] = f2b(a[r][0] + b2f(rq[r][0]));
      pk[1] = f2b(a[r][1] + b2f(rq[r][1]));
      *reinterpret_cast<u16x2*>(ob + r*256) = pk;
    }
  }
}

__global__ void finalize_k(const float* __restrict__ st,
                           const float* __restrict__ gamma,
                           const float* __restrict__ beta,
                           float* __restrict__ out)   // scale[512], shift[512]
{
  int o = blockIdx.x*256 + threadIdx.x;
  const float inv = 1.f / 131072.f;                   // B*N*R
  float mean = st[o] * inv;
  float var  = st[512 + o] * inv - mean*mean;
  float sc   = gamma[o] * rsqrtf(var + 1e-5f);
  out[o]       = sc;
  out[512 + o] = beta[o] - mean * sc;
}

// ---------------------------------------------------------------------------
extern "C" void kernel_launch(void* const* d_in, const int* in_sizes, int n_in,
                              void* d_out, int out_size, void* d_ws, size_t ws_size,
                              hipStream_t stream)
{
  (void)in_sizes; (void)n_in; (void)out_size; (void)ws_size;
  const float* queries = (const float*)d_in[0];
  const float* feats   = (const float*)d_in[1];
  const float* Wq = (const float*)d_in[2];
  const float* bq = (const float*)d_in[3];
  const float* Wk = (const float*)d_in[4];
  const float* bk = (const float*)d_in[5];
  const float* Wv = (const float*)d_in[6];
  const float* bv = (const float*)d_in[7];
  const float* W1 = (const float*)d_in[8];
  const float* b1 = (const float*)d_in[9];
  const float* gamma = (const float*)d_in[10];
  const float* beta  = (const float*)d_in[11];
  const float* W2 = (const float*)d_in[12];
  const float* b2 = (const float*)d_in[13];

  char* ws = (char*)d_ws;
  u16*   h1T   = (u16*)ws;
  u16*   qrT   = (u16*)(ws + 134217728L);
  u16*   qT    = (u16*)(ws + 201326592L);
  u16*   aggT  = (u16*)(ws + 268435456L);
  float* stats = (float*)(ws + 335544320L);
  float* scale = stats + 1024;
  float* shift = stats + 1536;
  u16*   wT    = (u16*)(ws + 335552512L);
  u16*   wKV   = wT;                 // 512 x 256
  u16*   wQ    = wT + 131072;        // 256 x 256
  u16*   wW1   = wT + 196608;        // 512 x 256
  u16*   wW2   = wT + 327680;        // 256 x 512
  float* bKV   = (float*)(wT + 458752);

  cvtW_k<<<dim3(230), 256, 0, stream>>>(Wk, Wv, Wq, W1, W2, wT,
                                        bk, bv, bKV, stats);

  // queries -> qrT bf16 [B][NRQ][256]
  transpose_k<<<dim3(NRQ/64, NB), 256, 0, stream>>>(queries, qrT, NRQ, (long)NRQ*256);

  // qT = qrT @ Wq^T + bq
  gemm_k<0, 256><<<dim3(512, 1, NB), 256, 0, stream>>>(
      qrT, (long)NRQ*256, 2, wQ, bq,
      qT, (long)NRQ*256, 256, nullptr, nullptr, nullptr, nullptr,
      nullptr, nullptr, 0);

  // fused kv-proj + attention (reads fp32 feats directly) -> aggT
  kvattn_k<<<dim3(NKF/128, NB), 1024, 0, stream>>>(
      feats, wKV, bKV, qT, qrT, aggT);

  // h1 = aggT @ W1^T + b1 -> bf16 + BN stats
  gemm_k<1, 256><<<dim3(1024, 1, NB), 256, 0, stream>>>(
      aggT, (long)NRQ*256, 4, wW1, b1,
      h1T, (long)NRQ*512, 512, stats, stats + 512, nullptr, nullptr,
      nullptr, nullptr, 0);

  finalize_k<<<dim3(2), 256, 0, stream>>>(stats, gamma, beta, scale);

  // d_out = relu( relu(bn(h1)) @ W2^T + b2 + aggT ) -> fp32 [B][256][NRQ]
  gemm_k<3, 512><<<dim3(512, 1, NB), 256, 0, stream>>>(
      h1T, (long)NRQ*512, 2, wW2, b2,
      nullptr, 0, 256, nullptr, nullptr, scale, shift,
      aggT, (float*)d_out, (long)256*NRQ);
}

// Round 14
// 657.825 us; speedup vs baseline: 1.0145x; 1.0145x over previous
//
#include <hip/hip_runtime.h>
#include <hip/hip_bf16.h>

#define NB 4
#define NRQ 32768      // per-batch q-side rows  (n*4)
#define NKF 131072     // per-batch feats rows   (n*16)

using u16 = unsigned short;
typedef short bf16x8 __attribute__((ext_vector_type(8)));
typedef float f32x4  __attribute__((ext_vector_type(4)));
typedef u16   u16x8  __attribute__((ext_vector_type(8)));
typedef u16   u16x4  __attribute__((ext_vector_type(4)));
typedef u16   u16x2  __attribute__((ext_vector_type(2)));

#if defined(__has_builtin)
#  if __has_builtin(__builtin_amdgcn_fdot2_f32_bf16)
#    define HAVE_DOT2 1
#  endif
#endif
#ifndef HAVE_DOT2
#  define HAVE_DOT2 0
#endif

#if HAVE_DOT2
typedef __bf16 bfv2 __attribute__((ext_vector_type(2)));
union bpack  { bf16x8 v; bfv2 p[4]; };
union bpack4 { u16x4  v; bfv2 p[2]; };
__device__ __forceinline__ float dot2(bfv2 a, bfv2 b, float c){
  return __builtin_amdgcn_fdot2_f32_bf16(a, b, c, false);
}
#endif
union vpack  { bf16x8 v; u16 e[8]; };
union vpack4 { u16x4 v; u16 e[4]; };

__device__ __forceinline__ u16 f2b(float f){
  __hip_bfloat16 h = __float2bfloat16(f);   // native cvt, RNE
  return *reinterpret_cast<u16*>(&h);
}
__device__ __forceinline__ float b2f(u16 v){
  return __uint_as_float(((unsigned)v) << 16);
}

#define GLOAD16(g, l) __builtin_amdgcn_global_load_lds( \
    (const __attribute__((address_space(1))) unsigned int*)(g), \
    (__attribute__((address_space(3))) unsigned int*)(l), 16, 0, 0)

// ---------------------------------------------------------------------------
// Weight preconvert fp32 -> bf16 (stacked) + bias stack + stat zero (merged)
// ---------------------------------------------------------------------------
__global__ __launch_bounds__(256) void cvtW_k(
    const float* __restrict__ Wk, const float* __restrict__ Wv,
    const float* __restrict__ Wq, const float* __restrict__ W1,
    const float* __restrict__ W2, u16* __restrict__ wT,
    const float* __restrict__ bk, const float* __restrict__ bv,
    float* __restrict__ bKV, float* __restrict__ stats)
{
  if (blockIdx.x >= 224){
    int i = (blockIdx.x - 224) * 256 + threadIdx.x;
    if (i < 512)       bKV[i] = (i < 256) ? bk[i] : bv[i - 256];
    else if (i < 1536) stats[i - 512] = 0.f;
    return;
  }
  long e = ((long)blockIdx.x * 256 + threadIdx.x) * 8;
  const float* src; long off;
  if      (e < 65536)  { src = Wk; off = e; }
  else if (e < 131072) { src = Wv; off = e - 65536; }
  else if (e < 196608) { src = Wq; off = e - 131072; }
  else if (e < 327680) { src = W1; off = e - 196608; }
  else                 { src = W2; off = e - 327680; }
  float4 f0 = *reinterpret_cast<const float4*>(src + off);
  float4 f1 = *reinterpret_cast<const float4*>(src + off + 4);
  u16x8 p;
  p[0]=f2b(f0.x); p[1]=f2b(f0.y); p[2]=f2b(f0.z); p[3]=f2b(f0.w);
  p[4]=f2b(f1.x); p[5]=f2b(f1.y); p[6]=f2b(f1.z); p[7]=f2b(f1.w);
  *reinterpret_cast<u16x8*>(wT + e) = p;
}

// ---------------------------------------------------------------------------
// Transpose+convert: in fp32 [B][256][NCtot] -> out bf16 [B][NCtot][256].
// ---------------------------------------------------------------------------
__global__ __launch_bounds__(256) void transpose_k(
    const float* __restrict__ in, u16* __restrict__ out,
    int NCtot, long outBatch)
{
  __shared__ u16 sT[64][264];
  const int t = threadIdx.x, b = blockIdx.y;
  const int nr0 = blockIdx.x * 64;
  const int cb = t >> 2, nrq = t & 3;
  const long ib = (long)b * 256 * NCtot + nr0;

  #pragma unroll
  for (int ci = 0; ci < 4; ++ci){
    const int c = cb + ci * 64;
    const float* src = in + ib + (long)c * NCtot + nrq * 16;
    #pragma unroll
    for (int j = 0; j < 4; ++j){
      float4 f = *reinterpret_cast<const float4*>(src + j * 4);
      int nr = nrq * 16 + j * 4;
      sT[nr+0][c] = f2b(f.x); sT[nr+1][c] = f2b(f.y);
      sT[nr+2][c] = f2b(f.z); sT[nr+3][c] = f2b(f.w);
    }
  }
  __syncthreads();
  const int row = t >> 2, qtr = t & 3;
  u16* orow = out + (long)b * outBatch + (long)(nr0 + row) * 256 + qtr * 64;
  #pragma unroll
  for (int i = 0; i < 8; ++i)
    *reinterpret_cast<u16x8*>(orow + i * 8) =
        *reinterpret_cast<const u16x8*>(&sT[row][qtr * 64 + i * 8]);
}

// ---------------------------------------------------------------------------
// GEMM: C[rows x NCH] = A[rows x KD] (bf16 k-contig) * Wb[NCH x KD]^T + bias.
// MODE 0: bf16 C. MODE 1: + per-ch sum/sumsq atomics.
// MODE 3: A reg-staged with per-k BN scale/shift+relu; epilogue
//         out = relu(acc+bias+residT) -> fp32 outF [ch][row].
// ---------------------------------------------------------------------------
template<int MODE, int KD>
__global__ __launch_bounds__(256) void gemm_k(
    const u16* __restrict__ A, long aBatch, int chTiles,
    const u16* __restrict__ Wb, const float* __restrict__ bias,
    u16* __restrict__ outH, long oBatch, int NCH,
    float* __restrict__ statSum, float* __restrict__ statSq,
    const float* __restrict__ xsc, const float* __restrict__ xsh,
    const u16* __restrict__ residT,
    float* __restrict__ outF, long fBatch)
{
  __shared__ __align__(16) char sA[2][16384];
  __shared__ __align__(16) char sB[2][16384];

  const int t = threadIdx.x, lane = t & 63, wid = t >> 6;
  const int wm = wid >> 1, wn = wid & 1;
  const int b = blockIdx.z;

  const int nwg = gridDim.x, orig = blockIdx.x;
  const int qq = nwg >> 3, rr = nwg & 7, xcd = orig & 7, pos = orig >> 3;
  const int wg = (xcd < rr ? xcd * (qq + 1) : rr * (qq + 1) + (xcd - rr) * qq) + pos;
  const int rowT = wg / chTiles, chT = wg % chTiles;

  const u16* Ab = A + (long)b * aBatch + (long)rowT * 128 * KD;
  const u16* Wt = Wb + (long)chT * 128 * KD;
  const int sub = lane >> 3, kc8 = ((lane & 7) ^ sub) * 8;

  f32x4 acc[4][4];
  #pragma unroll
  for (int i = 0; i < 4; ++i)
    #pragma unroll
    for (int j = 0; j < 4; ++j) acc[i][j] = (f32x4){0.f,0.f,0.f,0.f};

  auto STAGE = [&](int buf, int ks){
    const int k0 = ks * 64;
    if constexpr (MODE == 3){
      const int wrow = t >> 1, whalf = t & 1;
      const u16* arow = Ab + (long)wrow * KD + k0 + whalf * 32;
      #pragma unroll
      for (int i = 0; i < 4; ++i){
        u16x8 v = *reinterpret_cast<const u16x8*>(arow + i * 8);
        const int kb = k0 + whalf*32 + i*8;
        float4 s0 = *reinterpret_cast<const float4*>(xsc + kb);
        float4 s1 = *reinterpret_cast<const float4*>(xsc + kb + 4);
        float4 h0 = *reinterpret_cast<const float4*>(xsh + kb);
        float4 h1 = *reinterpret_cast<const float4*>(xsh + kb + 4);
        u16x8 o;
        o[0]=f2b(fmaxf(b2f(v[0])*s0.x+h0.x,0.f));
        o[1]=f2b(fmaxf(b2f(v[1])*s0.y+h0.y,0.f));
        o[2]=f2b(fmaxf(b2f(v[2])*s0.z+h0.z,0.f));
        o[3]=f2b(fmaxf(b2f(v[3])*s0.w+h0.w,0.f));
        o[4]=f2b(fmaxf(b2f(v[4])*s1.x+h1.x,0.f));
        o[5]=f2b(fmaxf(b2f(v[5])*s1.y+h1.y,0.f));
        o[6]=f2b(fmaxf(b2f(v[6])*s1.z+h1.z,0.f));
        o[7]=f2b(fmaxf(b2f(v[7])*s1.w+h1.w,0.f));
        *reinterpret_cast<u16x8*>(
            sA[buf] + ((wrow*128 + whalf*64 + i*16) ^ ((wrow & 7) << 4))) = o;
      }
      #pragma unroll
      for (int i = 0; i < 4; ++i){
        const int chunk = wid * 4 + i;
        GLOAD16(Wt + (long)(chunk*8 + sub)*KD + k0 + kc8, sB[buf] + chunk*1024);
      }
    } else {
      #pragma unroll
      for (int i = 0; i < 4; ++i){
        const int chunk = wid * 4 + i;
        GLOAD16(Ab + (long)(chunk*8 + sub)*KD + k0 + kc8, sA[buf] + chunk*1024);
        GLOAD16(Wt + (long)(chunk*8 + sub)*KD + k0 + kc8, sB[buf] + chunk*1024);
      }
    }
  };

  constexpr int NT = KD / 64;
  STAGE(0, 0);
  __syncthreads();
  int cur = 0;
  for (int ks = 0; ks < NT; ++ks){
    if (ks + 1 < NT) STAGE(cur ^ 1, ks + 1);
    const char* pA = sA[cur]; const char* pB = sB[cur];
    #pragma unroll
    for (int kk = 0; kk < 2; ++kk){
      bf16x8 af[4], bf[4];
      #pragma unroll
      for (int mi = 0; mi < 4; ++mi){
        int m = wm*64 + mi*16 + (lane & 15);
        af[mi] = *reinterpret_cast<const bf16x8*>(
            pA + ((m*128 + kk*64 + (lane>>4)*16) ^ ((m & 7) << 4)));
      }
      #pragma unroll
      for (int ni = 0; ni < 4; ++ni){
        int c = wn*64 + ni*16 + (lane & 15);
        bf[ni] = *reinterpret_cast<const bf16x8*>(
            pB + ((c*128 + kk*64 + (lane>>4)*16) ^ ((c & 7) << 4)));
      }
      #pragma unroll
      for (int mi = 0; mi < 4; ++mi)
        #pragma unroll
        for (int ni = 0; ni < 4; ++ni)
          acc[mi][ni] = __builtin_amdgcn_mfma_f32_16x16x32_bf16(
              af[mi], bf[ni], acc[mi][ni], 0, 0, 0);
    }
    __syncthreads();
    cur ^= 1;
  }

  int chI[4]; float bv[4];
  #pragma unroll
  for (int ni = 0; ni < 4; ++ni){
    int ch = chT*128 + wn*64 + ni*16 + (lane & 15);
    chI[ni] = ch;
    bv[ni] = bias[ch];
  }
  if (MODE != 3){
    float s[4] = {0,0,0,0}, sq[4] = {0,0,0,0};
    u16* outb = outH + (long)b * oBatch;
    #pragma unroll
    for (int mi = 0; mi < 4; ++mi){
      #pragma unroll
      for (int j = 0; j < 4; ++j){
        const long row = rowT*128 + wm*64 + mi*16 + (lane>>4)*4 + j;
        #pragma unroll
        for (int ni = 0; ni < 4; ++ni){
          float v = acc[mi][ni][j] + bv[ni];
          outb[row * NCH + chI[ni]] = f2b(v);
          if (MODE == 1){ s[ni] += v; sq[ni] += v * v; }
        }
      }
    }
    if (MODE == 1){
      #pragma unroll
      for (int ni = 0; ni < 4; ++ni){
        s[ni]  += __shfl_xor(s[ni], 16);  s[ni]  += __shfl_xor(s[ni], 32);
        sq[ni] += __shfl_xor(sq[ni], 16); sq[ni] += __shfl_xor(sq[ni], 32);
      }
      if (lane < 16){
        #pragma unroll
        for (int ni = 0; ni < 4; ++ni){
          atomicAdd(&statSum[chI[ni]], s[ni]);
          atomicAdd(&statSq[chI[ni]],  sq[ni]);
        }
      }
    }
  } else {
    const u16* rb = residT + (long)b * ((long)NRQ * 256);
    #pragma unroll
    for (int mi = 0; mi < 4; ++mi){
      const int nr0 = rowT*128 + wm*64 + mi*16 + (lane>>4)*4;
      #pragma unroll
      for (int ni = 0; ni < 4; ++ni){
        float4 o;
        o.x = fmaxf(acc[mi][ni][0] + bv[ni] + b2f(rb[(long)(nr0+0)*256 + chI[ni]]), 0.f);
        o.y = fmaxf(acc[mi][ni][1] + bv[ni] + b2f(rb[(long)(nr0+1)*256 + chI[ni]]), 0.f);
        o.z = fmaxf(acc[mi][ni][2] + bv[ni] + b2f(rb[(long)(nr0+2)*256 + chI[ni]]), 0.f);
        o.w = fmaxf(acc[mi][ni][3] + bv[ni] + b2f(rb[(long)(nr0+3)*256 + chI[ni]]), 0.f);
        *reinterpret_cast<float4*>(outF + (long)b*fBatch + (long)chI[ni]*NRQ + nr0) = o;
      }
    }
  }
}

// ---------------------------------------------------------------------------
// Fused kv-projection + attention, v8b: 64 rows PER WAVE (halves LDS W-read
// redundancy per CU). Block = 512 thr (8 waves: 2 wr x 4 wc), 128 rows
// (8 pts) x 512 ch, BK=32. Attention: 1 wave per point, 4 ch per lane.
// ---------------------------------------------------------------------------
__global__ __launch_bounds__(512, 2) void kvattn_k(
    const float* __restrict__ feats, const u16* __restrict__ wKV,
    const float* __restrict__ bKV, const u16* __restrict__ qT,
    const u16* __restrict__ qrT, u16* __restrict__ aggT)
{
  __shared__ __align__(16) char LDS[142848];
  char*  sAg = LDS;                     // 2 x 128 x 72 = 18432
  char*  sW  = LDS + 18432;             // 2 x 32768 (ends 83968)
  char*  sK  = LDS;                     // attn: [128 r][528B] plain
  char*  sV  = LDS + 67584;             // attn: [128 r][520B] plain
  float* sSf = (float*)(LDS + 134144);  // P fp32: [32 ph][68 dw]

  const int t = threadIdx.x, lane = t & 63, wid = t >> 6;   // wid 0..7
  const int wr = wid >> 2, wc = wid & 3;       // 2 x 4 waves for GEMM
  const int b = blockIdx.y;
  const long row0 = (long)blockIdx.x * 128;

  const int chL = t >> 4, nq = t & 15;         // k-elem (0..31), row-slot
  const float* fbase = feats + (long)b * 256 * NKF + row0 + nq;

  auto STAGEW = [&](int buf, int ks){
    const int k0 = ks * 32;
    #pragma unroll
    for (int i = 0; i < 4; ++i){
      const int cw = wid * 4 + i;                   // 32 chunks x 1KB
      const int ch = cw * 16 + (lane >> 2), jd = lane & 3;
      GLOAD16(wKV + (long)ch * 256 + k0 + ((jd ^ ((ch >> 1) & 3)) * 8),
              sW + buf * 32768 + cw * 1024);
    }
  };
  auto LOADA = [&](int ks, float* ar){
    const float* src = fbase + (long)(ks * 32 + chL) * NKF;
    #pragma unroll
    for (int i = 0; i < 8; ++i) ar[i] = src[16 * i];
  };
  auto WRITEA = [&](int buf, const float* ar){
    #pragma unroll
    for (int i = 0; i < 8; ++i){
      const int r = nq + 16 * i;
      *reinterpret_cast<u16*>(sAg + buf*9216 + r*72 + chL*2) = f2b(ar[i]);
    }
  };

  f32x4 acc[4][8];
  #pragma unroll
  for (int i = 0; i < 4; ++i)
    #pragma unroll
    for (int j = 0; j < 8; ++j) acc[i][j] = (f32x4){0.f,0.f,0.f,0.f};

  float aR[8];
  {
    LOADA(0, aR);
    STAGEW(0, 0);
    WRITEA(0, aR);
  }
  __syncthreads();

  int cur = 0;
  const int jq = lane >> 4;
  #pragma unroll
  for (int ks = 0; ks < 8; ++ks){
    if (ks < 7){
      LOADA(ks + 1, aR);
      STAGEW(cur ^ 1, ks + 1);
    }
    const char* pA = sAg + cur * 9216;
    const char* pW = sW  + cur * 32768;
    bf16x8 af[4];
    #pragma unroll
    for (int mi = 0; mi < 4; ++mi){
      const int m = wr*64 + mi*16 + (lane & 15);
      af[mi] = *reinterpret_cast<const bf16x8*>(pA + m*72 + jq*16);
    }
    __builtin_amdgcn_s_setprio(1);
    #pragma unroll
    for (int ni = 0; ni < 8; ++ni){
      const int ch = wc*128 + ni*16 + (lane & 15);
      bf16x8 bf = *reinterpret_cast<const bf16x8*>(
          pW + ch*64 + (((jq ^ ((ch>>1)&3)) * 16)));
      #pragma unroll
      for (int mi = 0; mi < 4; ++mi)
        acc[mi][ni] = __builtin_amdgcn_mfma_f32_16x16x32_bf16(
            af[mi], bf, acc[mi][ni], 0, 0, 0);
    }
    __builtin_amdgcn_s_setprio(0);
    if (ks < 7) WRITEA(cur ^ 1, aR);
    __syncthreads();
    cur ^= 1;
  }

  // ---- C (+bias) -> sK (ch 0-255) / sV (ch 256-511), plain pitches
  {
    float bv[8];
    #pragma unroll
    for (int ni = 0; ni < 8; ++ni) bv[ni] = bKV[wc*128 + ni*16 + (lane & 15)];
    char* dst = (wc < 2) ? sK : sV;
    const int pitch = (wc < 2) ? 528 : 520;
    const int chb = (wc & 1) * 128;
    #pragma unroll
    for (int mi = 0; mi < 4; ++mi){
      #pragma unroll
      for (int ni = 0; ni < 8; ++ni){
        const int ch = chb + ni*16 + (lane & 15);
        #pragma unroll
        for (int j = 0; j < 4; ++j){
          const int r = wr*64 + mi*16 + (lane>>4)*4 + j;
          *reinterpret_cast<u16*>(dst + r*pitch + ch*2) =
              f2b(acc[mi][ni][j] + bv[ni]);
        }
      }
    }
  }

  // residual prefetch (consumed in phase B; latency hidden under phase A)
  const int p = wid;                           // 1 wave per point
  const int nqg = blockIdx.x * 8 + p;
  const int c0 = lane * 4;                     // 4 channels per lane (0..252)
  u16x4 rq[4];
  {
    const u16* rqp = qrT + ((long)b*NRQ + (long)nqg*4)*256 + c0;
    #pragma unroll
    for (int r = 0; r < 4; ++r)
      rq[r] = *reinterpret_cast<const u16x4*>(rqp + r*256);
  }
  __syncthreads();

  // ---- phase A: logits + softmax; lane = (h, kk); 4 r's per lane
  {
    const int h = lane >> 4, kk = lane & 15;
    const u16* qb = qT + ((long)b*NRQ + (long)nqg*4)*256 + h*64;
    const char* kr = sK + (p*16 + kk)*528 + h*128;
    float l[4] = {0.f, 0.f, 0.f, 0.f};
#if HAVE_DOT2
    #pragma unroll
    for (int d8 = 0; d8 < 8; ++d8){
      bpack K8;
      K8.v = *reinterpret_cast<const bf16x8*>(kr + d8*16);
      #pragma unroll
      for (int r = 0; r < 4; ++r){
        bpack Q;
        Q.v = *reinterpret_cast<const bf16x8*>(qb + r*256 + d8*8);
        #pragma unroll
        for (int pi = 0; pi < 4; ++pi) l[r] = dot2(K8.p[pi], Q.p[pi], l[r]);
      }
    }
#else
    #pragma unroll
    for (int d8 = 0; d8 < 8; ++d8){
      vpack K8;
      K8.v = *reinterpret_cast<const bf16x8*>(kr + d8*16);
      #pragma unroll
      for (int r = 0; r < 4; ++r){
        vpack Q;
        Q.v = *reinterpret_cast<const bf16x8*>(qb + r*256 + d8*8);
        #pragma unroll
        for (int e = 0; e < 8; ++e) l[r] = fmaf(b2f(K8.e[e]), b2f(Q.e[e]), l[r]);
      }
    }
#endif
    float4 prob;
    #pragma unroll
    for (int r = 0; r < 4; ++r){
      float x = l[r] * 0.125f;
      float m = x;
      #pragma unroll
      for (int off = 1; off < 16; off <<= 1) m = fmaxf(m, __shfl_xor(m, off));
      float e = __expf(x - m);
      float ssum = e;
      #pragma unroll
      for (int off = 1; off < 16; off <<= 1) ssum += __shfl_xor(ssum, off);
      float pr = e / ssum;
      if (r == 0) prob.x = pr; else if (r == 1) prob.y = pr;
      else if (r == 2) prob.z = pr; else prob.w = pr;
    }
    *reinterpret_cast<float4*>(sSf + (p*4 + h)*68 + kk*4) = prob;
  }
  __syncthreads();

  // ---- phase B: agg = v @ soft^T + residual. lane -> 4 channels
  {
    const int h = c0 >> 6;                     // head of these 4 channels
    const char* vrow = sV + (p*16)*520;
    const float* ss = sSf + (p*4 + h)*68;
    float a[4][4] = {};
    #pragma unroll
    for (int kk = 0; kk < 16; ++kk){
      vpack4 vv;
      vv.v = *reinterpret_cast<const u16x4*>(vrow + kk*520 + c0*2);
      float4 sv = *reinterpret_cast<const float4*>(ss + kk*4);
      #pragma unroll
      for (int cc = 0; cc < 4; ++cc){
        float vf = b2f(vv.e[cc]);
        a[0][cc] += sv.x*vf; a[1][cc] += sv.y*vf;
        a[2][cc] += sv.z*vf; a[3][cc] += sv.w*vf;
      }
    }
    u16* ob = aggT + ((long)b*NRQ + (long)nqg*4)*256 + c0;
    #pragma unroll
    for (int r = 0; r < 4; ++r){
      u16x4 pk;
      #pragma unroll
      for (int cc = 0; cc < 4; ++cc) pk[cc] = f2b(a[r][cc] + b2f(rq[r][cc]));
      *reinterpret_cast<u16x4*>(ob + r*256) = pk;
    }
  }
}

__global__ void finalize_k(const float* __restrict__ st,
                           const float* __restrict__ gamma,
                           const float* __restrict__ beta,
                           float* __restrict__ out)   // scale[512], shift[512]
{
  int o = blockIdx.x*256 + threadIdx.x;
  const float inv = 1.f / 131072.f;                   // B*N*R
  float mean = st[o] * inv;
  float var  = st[512 + o] * inv - mean*mean;
  float sc   = gamma[o] * rsqrtf(var + 1e-5f);
  out[o]       = sc;
  out[512 + o] = beta[o] - mean * sc;
}

// ---------------------------------------------------------------------------
extern "C" void kernel_launch(void* const* d_in, const int* in_sizes, int n_in,
                              void* d_out, int out_size, void* d_ws, size_t ws_size,
                              hipStream_t stream)
{
  (void)in_sizes; (void)n_in; (void)out_size; (void)ws_size;
  const float* queries = (const float*)d_in[0];
  const float* feats   = (const float*)d_in[1];
  const float* Wq = (const float*)d_in[2];
  const float* bq = (const float*)d_in[3];
  const float* Wk = (const float*)d_in[4];
  const float* bk = (const float*)d_in[5];
  const float* Wv = (const float*)d_in[6];
  const float* bv = (const float*)d_in[7];
  const float* W1 = (const float*)d_in[8];
  const float* b1 = (const float*)d_in[9];
  const float* gamma = (const float*)d_in[10];
  const float* beta  = (const float*)d_in[11];
  const float* W2 = (const float*)d_in[12];
  const float* b2 = (const float*)d_in[13];

  char* ws = (char*)d_ws;
  u16*   h1T   = (u16*)ws;
  u16*   qrT   = (u16*)(ws + 134217728L);
  u16*   qT    = (u16*)(ws + 201326592L);
  u16*   aggT  = (u16*)(ws + 268435456L);
  float* stats = (float*)(ws + 335544320L);
  float* scale = stats + 1024;
  float* shift = stats + 1536;
  u16*   wT    = (u16*)(ws + 335552512L);
  u16*   wKV   = wT;                 // 512 x 256
  u16*   wQ    = wT + 131072;        // 256 x 256
  u16*   wW1   = wT + 196608;        // 512 x 256
  u16*   wW2   = wT + 327680;        // 256 x 512
  float* bKV   = (float*)(wT + 458752);

  cvtW_k<<<dim3(230), 256, 0, stream>>>(Wk, Wv, Wq, W1, W2, wT,
                                        bk, bv, bKV, stats);

  // queries -> qrT bf16 [B][NRQ][256]
  transpose_k<<<dim3(NRQ/64, NB), 256, 0, stream>>>(queries, qrT, NRQ, (long)NRQ*256);

  // qT = qrT @ Wq^T + bq
  gemm_k<0, 256><<<dim3(512, 1, NB), 256, 0, stream>>>(
      qrT, (long)NRQ*256, 2, wQ, bq,
      qT, (long)NRQ*256, 256, nullptr, nullptr, nullptr, nullptr,
      nullptr, nullptr, 0);

  // fused kv-proj + attention (reads fp32 feats directly) -> aggT
  kvattn_k<<<dim3(NKF/128, NB), 512, 0, stream>>>(
      feats, wKV, bKV, qT, qrT, aggT);

  // h1 = aggT @ W1^T + b1 -> bf16 + BN stats
  gemm_k<1, 256><<<dim3(1024, 1, NB), 256, 0, stream>>>(
      aggT, (long)NRQ*256, 4, wW1, b1,
      h1T, (long)NRQ*512, 512, stats, stats + 512, nullptr, nullptr,
      nullptr, nullptr, 0);

  finalize_k<<<dim3(2), 256, 0, stream>>>(stats, gamma, beta, scale);

  // d_out = relu( relu(bn(h1)) @ W2^T + b2 + aggT ) -> fp32 [B][256][NRQ]
  gemm_k<3, 512><<<dim3(512, 1, NB), 256, 0, stream>>>(
      h1T, (long)NRQ*512, 2, wW2, b2,
      nullptr, 0, 256, nullptr, nullptr, scale, shift,
      aggT, (float*)d_out, (long)256*NRQ);
}